// Round 12
// baseline (1213.386 us; speedup 1.0000x reference)
//
#include <hip/hip_runtime.h>
#include <cstdint>

#define N_NODES 100000
#define N_EDGES 3200000
#define N_GRAPHS 64
#define HDIM 256
#define F_IN 128

#define BUCKET_BITS 7
#define NPB 128                                 // nodes per bucket
#define N_BUCKETS ((N_NODES + NPB - 1) / NPB)   // 782
#define CHUNK 8192
#define NCHUNK ((N_EDGES + CHUNK - 1) / CHUNK)  // 391

typedef __attribute__((ext_vector_type(8))) short bf16x8;
typedef __attribute__((ext_vector_type(4))) float f32x4;
typedef __attribute__((ext_vector_type(2))) float f32x2;

// ---------------- bf16 helpers ----------------
__device__ __forceinline__ unsigned short f2bf(float f) {
    unsigned int b = __float_as_uint(f);
    b = (b + 0x7FFFu + ((b >> 16) & 1u)) >> 16;
    return (unsigned short)b;
}
__device__ __forceinline__ float bf2f(unsigned short u) {
    return __uint_as_float((unsigned int)u << 16);
}

// ---------------- fp8 e4m3 helpers (HW cvt) ----------------
__device__ __forceinline__ unsigned int pack4_fp8(float a, float b, float c, float d) {
    int v = 0;
    v = __builtin_amdgcn_cvt_pk_fp8_f32(a, b, v, false);  // bytes 0,1
    v = __builtin_amdgcn_cvt_pk_fp8_f32(c, d, v, true);   // bytes 2,3
    return (unsigned int)v;
}
__device__ __forceinline__ unsigned char pack1_fp8(float a) {
    int v = __builtin_amdgcn_cvt_pk_fp8_f32(a, a, 0, false);
    return (unsigned char)(v & 0xFF);
}

// ---------------- utility ----------------
__global__ void zero_f(float* p, int n) {
    int i = blockIdx.x * blockDim.x + threadIdx.x;
    if (i < n) p[i] = 0.0f;
}

// ---------------- atomic-free multisplit CSR build ----------------
__global__ __launch_bounds__(256) void block_count(const int* __restrict__ dst,
                                                   int* __restrict__ counts, int nE) {
    __shared__ int hist[N_BUCKETS];
    int blk = blockIdx.x, t = threadIdx.x;
    for (int i = t; i < N_BUCKETS; i += 256) hist[i] = 0;
    __syncthreads();
    int lo = blk * CHUNK;
    int hi = lo + CHUNK < nE ? lo + CHUNK : nE;
    for (int i = lo + t; i < hi; i += 256) atomicAdd(&hist[dst[i] >> BUCKET_BITS], 1);
    __syncthreads();
    for (int i = t; i < N_BUCKETS; i += 256) counts[blk * N_BUCKETS + i] = hist[i];
}

__global__ __launch_bounds__(256) void bucket_totals(const int* __restrict__ counts,
                                                     int* __restrict__ tot) {
    __shared__ int red[256];
    int b = blockIdx.x, t = threadIdx.x;
    int s = 0;
    for (int blk = t; blk < NCHUNK; blk += 256) s += counts[blk * N_BUCKETS + b];
    red[t] = s;
    __syncthreads();
    for (int o = 128; o > 0; o >>= 1) {
        if (t < o) red[t] += red[t + o];
        __syncthreads();
    }
    if (t == 0) tot[b] = red[0];
}

__global__ __launch_bounds__(1024) void scan_buckets(const int* __restrict__ tot,
                                                     int* __restrict__ base, int nb) {
    __shared__ int lds[1024];
    int t = threadIdx.x;
    int v = (t < nb) ? tot[t] : 0;
    lds[t] = v;
    __syncthreads();
    for (int off = 1; off < 1024; off <<= 1) {
        int a = (t >= off) ? lds[t - off] : 0;
        __syncthreads();
        lds[t] += a;
        __syncthreads();
    }
    int excl = lds[t] - v;
    if (t < nb) base[t] = excl;
    if (t == nb) base[t] = excl;
}

__global__ __launch_bounds__(512) void column_scan(const int* __restrict__ counts,
                                                   const int* __restrict__ base,
                                                   int* __restrict__ offs) {
    __shared__ int lds[512];
    int b = blockIdx.x, t = threadIdx.x;
    int v = (t < NCHUNK) ? counts[t * N_BUCKETS + b] : 0;
    lds[t] = v;
    __syncthreads();
    for (int off = 1; off < 512; off <<= 1) {
        int a = (t >= off) ? lds[t - off] : 0;
        __syncthreads();
        lds[t] += a;
        __syncthreads();
    }
    if (t < NCHUNK) offs[t * N_BUCKETS + b] = base[b] + lds[t] - v;
}

__global__ __launch_bounds__(256) void block_scatter(const int* __restrict__ src,
                                                     const int* __restrict__ dst,
                                                     const int* __restrict__ offs,
                                                     unsigned int* __restrict__ rec, int nE) {
    __shared__ int cur[N_BUCKETS];
    int blk = blockIdx.x, t = threadIdx.x;
    for (int i = t; i < N_BUCKETS; i += 256) cur[i] = offs[blk * N_BUCKETS + i];
    __syncthreads();
    int lo = blk * CHUNK;
    int hi = lo + CHUNK < nE ? lo + CHUNK : nE;
    for (int i = lo + t; i < hi; i += 256) {
        int d = dst[i];
        int b = d >> BUCKET_BITS;
        int pos = atomicAdd(&cur[b], 1);  // LDS atomic
        rec[pos] = (unsigned int)src[i] | ((unsigned int)(d & (NPB - 1)) << 17);
    }
}

__global__ __launch_bounds__(512) void bucket_csr(const unsigned int* __restrict__ rec,
                                                  const int* __restrict__ base,
                                                  int* __restrict__ ptr, float* __restrict__ dinv,
                                                  int* __restrict__ csr_src, int n) {
    __shared__ int hist[NPB];
    __shared__ int sc[NPB];
    __shared__ int cur[NPB];
    int b = blockIdx.x;
    int lo = base[b], hi = base[b + 1];
    int t = threadIdx.x;
    if (t < NPB) hist[t] = 0;
    __syncthreads();
    for (int i = lo + t; i < hi; i += 512) atomicAdd(&hist[rec[i] >> 17], 1);
    __syncthreads();
    if (t < NPB) sc[t] = hist[t];
    __syncthreads();
    for (int off = 1; off < NPB; off <<= 1) {
        int a = (t < NPB && t >= off) ? sc[t - off] : 0;
        __syncthreads();
        if (t < NPB) sc[t] += a;
        __syncthreads();
    }
    if (t < NPB) {
        int node = b * NPB + t;
        int incl = sc[t];
        int excl = incl - hist[t];
        if (node < n) {
            ptr[node] = lo + incl;
            dinv[node] = rsqrtf((float)hist[t] + 1.0f);
        }
        cur[t] = lo + excl;
    }
    __syncthreads();
    for (int i = lo + t; i < hi; i += 512) {
        unsigned int r = rec[i];
        int pos = atomicAdd(&cur[r >> 17], 1);
        csr_src[pos] = (int)(r & 0x1FFFFu);
    }
}

// ---------------- x -> fp8 pre-scaled: x_pre[n] = fp8(dinv[n] * x[n]) ----------------
__global__ void convert_x_pre(const float* __restrict__ x, const float* __restrict__ dinv,
                              unsigned int* __restrict__ xp, int n) {
    int tid = blockIdx.x * blockDim.x + threadIdx.x;  // over n*F_IN/4
    if (tid >= n * (F_IN / 4)) return;
    int node = tid / (F_IN / 4);
    float di = dinv[node];
    float4 v = ((const float4*)x)[tid];
    xp[tid] = pack4_fp8(v.x * di, v.y * di, v.z * di, v.w * di);
}

// ---------------- pack W[K][256] fp32 -> hi/lo bf16 in MFMA B-fragment order ----------------
__global__ void pack_w(const float* __restrict__ W, unsigned short* __restrict__ hi,
                       unsigned short* __restrict__ lo, int K) {
    int idx = blockIdx.x * blockDim.x + threadIdx.x;
    if (idx >= K * HDIM) return;
    int k = idx >> 8, c = idx & 255;
    float w = W[idx];
    unsigned short h = f2bf(w);
    float hf = __uint_as_float((unsigned int)h << 16);
    unsigned short l = f2bf(w - hf);
    int pos = ((k >> 5) * 16 + (c >> 4)) * 512 + ((((k >> 3) & 3) * 16) + (c & 15)) * 8 + (k & 7);
    hi[pos] = h;
    lo[pos] = l;
}

// ---------------- XCD-affine column-sliced aggregation (fp8 in, bf16 out) ----------------
// F = features/row (fp8, 1 B each). Slice = 32 features, pinned to XCD via blockIdx%8.
// NSLICES = F/32. blockIdx = nodeblk*8 + slot; slice = slot % NSLICES;
// node group = slot / NSLICES. Wave: eg = lane>>3 (8 edges in parallel), cp = lane&7 (4 feats).
// out[node] = bf16( dinv[node] * ( h[node] + sum_s h[s] ) )  (h pre-scaled by dinv[s])
template <int F>
__global__ __launch_bounds__(256) void csr_agg_sliced(
    const unsigned char* __restrict__ h, const int* __restrict__ ptr,
    const int* __restrict__ csr, const float* __restrict__ dinv,
    unsigned short* __restrict__ out, int n) {
    constexpr int NSLICES = F / 32;
    constexpr int NODEGRP = 8 / NSLICES;  // 1 for F=256, 2 for F=128
    int slot = blockIdx.x & 7;
    int nodeblk = blockIdx.x >> 3;
    int wave = threadIdx.x >> 6, lane = threadIdx.x & 63;
    int slice = slot % NSLICES;
    int grp = slot / NSLICES;
    int node = nodeblk * (4 * NODEGRP) + grp * 4 + wave;
    if (node >= n) return;
    int eg = lane >> 3;       // edge group 0..7
    int cp = lane & 7;        // col part within slice
    int colbyte = slice * 32 + cp * 4;

    int begin = node ? ptr[node - 1] : 0;
    int end = ptr[node];

    // own row (counted once: eg==0 only; fp8 0x00000000 decodes to 0.0)
    unsigned int uown = 0;
    if (eg == 0) uown = *(const unsigned int*)(h + (size_t)node * F + colbyte);
    f32x2 a01 = __builtin_amdgcn_cvt_pk_f32_fp8((int)uown, false);
    f32x2 a23 = __builtin_amdgcn_cvt_pk_f32_fp8((int)uown, true);

    for (int i = begin; i < end; i += 32) {
        unsigned int uu[4];
#pragma unroll
        for (int j = 0; j < 4; j++) {
            int e = i + j * 8 + eg;
            unsigned int u = 0;
            if (e < end) {
                int s = csr[e];
                u = *(const unsigned int*)(h + (size_t)s * F + colbyte);
            }
            uu[j] = u;
        }
#pragma unroll
        for (int j = 0; j < 4; j++) {
            a01 += __builtin_amdgcn_cvt_pk_f32_fp8((int)uu[j], false);
            a23 += __builtin_amdgcn_cvt_pk_f32_fp8((int)uu[j], true);
        }
    }

    // butterfly reduce across edge groups (lane bits 3,4,5)
#pragma unroll
    for (int m = 8; m <= 32; m <<= 1) {
        a01.x += __shfl_xor(a01.x, m);
        a01.y += __shfl_xor(a01.y, m);
        a23.x += __shfl_xor(a23.x, m);
        a23.y += __shfl_xor(a23.y, m);
    }

    if (eg == 0) {
        float dn = dinv[node];
        uint2 o;
        o.x = (unsigned int)f2bf(a01.x * dn) | ((unsigned int)f2bf(a01.y * dn) << 16);
        o.y = (unsigned int)f2bf(a23.x * dn) | ((unsigned int)f2bf(a23.y * dn) << 16);
        *(uint2*)(out + (size_t)node * F + slice * 32 + cp * 4) = o;
    }
}

// ---------------- MFMA GEMM: act(A[n,K] @ (Whi+Wlo) + b) ----------------
// block: 4 waves = 64 rows x 256 cols; wave: 32 rows (2 strips) x 128 cols (8 ct)
// MODE 0: out fp8 = fp8(dinv[row]*relu(v))   (layer-1, feeds agg256)
// MODE 2: out bf16 = bf16(relu(v))           (layer-2, feeds pooling)
template <int K, int MODE>
__global__ __launch_bounds__(256, 3) void gemm_mfma(
    const unsigned short* __restrict__ A, const unsigned short* __restrict__ Whi,
    const unsigned short* __restrict__ Wlo, const float* __restrict__ bias,
    const float* __restrict__ dinv, void* __restrict__ outp, int n) {
    int wave = threadIdx.x >> 6, lane = threadIdx.x & 63;
    int quad = lane >> 4, l16 = lane & 15;
    int rowgrp = wave >> 1, colhalf = wave & 1;
    int rowbase = blockIdx.x * 64 + rowgrp * 32;

    f32x4 acc[2][8];
#pragma unroll
    for (int s = 0; s < 2; s++)
#pragma unroll
        for (int ct = 0; ct < 8; ct++) acc[s][ct] = (f32x4){0.f, 0.f, 0.f, 0.f};

    int r0 = rowbase + l16;
    int r1 = rowbase + 16 + l16;
    int rc0 = r0 < n ? r0 : n - 1;
    int rc1 = r1 < n ? r1 : n - 1;

    for (int kt = 0; kt < K / 32; kt++) {
        bf16x8 a0 = *(const bf16x8*)(A + (size_t)rc0 * K + kt * 32 + quad * 8);
        bf16x8 a1 = *(const bf16x8*)(A + (size_t)rc1 * K + kt * 32 + quad * 8);
        const unsigned short* wh = Whi + ((size_t)kt * 16 + colhalf * 8) * 512 + lane * 8;
        const unsigned short* wl = Wlo + ((size_t)kt * 16 + colhalf * 8) * 512 + lane * 8;
#pragma unroll
        for (int ct = 0; ct < 8; ct++) {
            bf16x8 bh = *(const bf16x8*)(wh + ct * 512);
            bf16x8 bl = *(const bf16x8*)(wl + ct * 512);
            acc[0][ct] = __builtin_amdgcn_mfma_f32_16x16x32_bf16(a0, bh, acc[0][ct], 0, 0, 0);
            acc[0][ct] = __builtin_amdgcn_mfma_f32_16x16x32_bf16(a0, bl, acc[0][ct], 0, 0, 0);
            acc[1][ct] = __builtin_amdgcn_mfma_f32_16x16x32_bf16(a1, bh, acc[1][ct], 0, 0, 0);
            acc[1][ct] = __builtin_amdgcn_mfma_f32_16x16x32_bf16(a1, bl, acc[1][ct], 0, 0, 0);
        }
    }

#pragma unroll
    for (int s = 0; s < 2; s++) {
#pragma unroll
        for (int ct = 0; ct < 8; ct++) {
            int col = colhalf * 128 + ct * 16 + l16;
            float b = bias[col];
#pragma unroll
            for (int r = 0; r < 4; r++) {
                int row = rowbase + s * 16 + quad * 4 + r;
                if (row < n) {
                    float v = acc[s][ct][r] + b;
                    v = v > 0.0f ? v : 0.0f;
                    if (MODE == 0) {
                        ((unsigned char*)outp)[(size_t)row * HDIM + col] = pack1_fp8(v * dinv[row]);
                    } else {
                        ((unsigned short*)outp)[(size_t)row * HDIM + col] = f2bf(v);
                    }
                }
            }
        }
    }
}

// ---------------- pooling (batch sorted -> run-length), bf16 input ----------------
__global__ void pool_sum_runs(const unsigned short* __restrict__ h, const int* __restrict__ batch,
                              float* __restrict__ pool, int n) {
    constexpr int ROWS = 128;
    int f = threadIdx.x;
    int r0 = blockIdx.x * ROWS;
    int rend = r0 + ROWS;
    if (rend > n) rend = n;
    float acc = 0.0f;
    int cur = batch[r0];
    for (int r = r0; r < rend; r++) {
        int g = batch[r];
        if (g != cur) {
            atomicAdd(&pool[cur * HDIM + f], acc);
            acc = 0.0f; cur = g;
        }
        acc += bf2f(h[(size_t)r * HDIM + f]);
    }
    atomicAdd(&pool[cur * HDIM + f], acc);
}

// ---------------- head: mean (cnt via binary search on sorted batch) + FC + log_softmax ----
__global__ void final_head(const float* __restrict__ pool, const int* __restrict__ batch,
                           const float* __restrict__ fcw, const float* __restrict__ fcb,
                           float* __restrict__ out, int n) {
    int g = threadIdx.x;
    if (g < N_GRAPHS) {
        int lo = 0, hi = n;
        while (lo < hi) { int m = (lo + hi) >> 1; if (batch[m] < g) lo = m + 1; else hi = m; }
        int b0 = lo;
        lo = 0; hi = n;
        while (lo < hi) { int m = (lo + hi) >> 1; if (batch[m] < g + 1) lo = m + 1; else hi = m; }
        int c = lo - b0;
        float cf = c > 1 ? (float)c : 1.0f;
        float inv = 1.0f / cf;
        float l0 = fcb[0], l1 = fcb[1];
        for (int f = 0; f < HDIM; f++) {
            float p = pool[g * HDIM + f] * inv;
            l0 += p * fcw[f * 2 + 0];
            l1 += p * fcw[f * 2 + 1];
        }
        float m = fmaxf(l0, l1);
        float lse = m + logf(expf(l0 - m) + expf(l1 - m));
        out[g * 2 + 0] = l0 - lse;
        out[g * 2 + 1] = l1 - lse;
    }
}

extern "C" void kernel_launch(void* const* d_in, const int* in_sizes, int n_in,
                              void* d_out, int out_size, void* d_ws, size_t ws_size,
                              hipStream_t stream) {
    const float* x = (const float*)d_in[0];
    const int* ei = (const int*)d_in[1];
    const int* batch = (const int*)d_in[2];
    const float* W1 = (const float*)d_in[3];
    const float* b1 = (const float*)d_in[4];
    const float* W2 = (const float*)d_in[5];
    const float* b2 = (const float*)d_in[6];
    const float* fcw = (const float*)d_in[7];
    const float* fcb = (const float*)d_in[8];
    float* out = (float*)d_out;

    const int* src = ei;
    const int* dst = ei + N_EDGES;

    // ---- workspace layout (bytes) ----
    char* ws = (char*)d_ws;
    float* dinv = (float*)ws;            ws += 4 * ((N_NODES + 255) & ~255);
    int* ptr = (int*)ws;                 ws += 4 * ((N_NODES + 255) & ~255);
    int* csr_src = (int*)ws;             ws += 4 * (size_t)N_EDGES;
    int* counts = (int*)ws;              ws += 4 * (size_t)NCHUNK * N_BUCKETS;
    int* offs = (int*)ws;                ws += 4 * (size_t)NCHUNK * N_BUCKETS;
    int* tot = (int*)ws;                 ws += 4 * 1024;
    int* bbase = (int*)ws;               ws += 4 * 1024;
    unsigned short* W1hi = (unsigned short*)ws; ws += 2 * F_IN * HDIM;
    unsigned short* W1lo = (unsigned short*)ws; ws += 2 * F_IN * HDIM;
    unsigned short* W2hi = (unsigned short*)ws; ws += 2 * HDIM * HDIM;
    unsigned short* W2lo = (unsigned short*)ws; ws += 2 * HDIM * HDIM;
    float* pool = (float*)ws;            ws += 4 * N_GRAPHS * HDIM;
    // R0 region (102.4MB): x_pre fp8 | A1 bf16 | h1_pre fp8; later h2 bf16 overlays start
    char* R0 = ws;                       ws += 4 * (size_t)N_NODES * HDIM;
    unsigned char* x_pre = (unsigned char*)R0;                                 // N*128 fp8
    unsigned short* A1 = (unsigned short*)(R0 + (size_t)N_NODES * F_IN);       // N*128 bf16
    unsigned char* h1_pre = (unsigned char*)(R0 + 3 * (size_t)N_NODES * F_IN); // N*256 fp8
    unsigned short* h2 = (unsigned short*)R0;                                  // N*256 bf16
    unsigned short* A2 = (unsigned short*)ws;  // N*256 bf16 (layer 2 only)
    // records overlay A2 (dead until layer 2): N_EDGES*4 = 12.8MB <= 51.2MB
    unsigned int* records = (unsigned int*)A2;

    // ---- atomic-free bucketed CSR build + dinv ----
    block_count<<<NCHUNK, 256, 0, stream>>>(dst, counts, N_EDGES);
    bucket_totals<<<N_BUCKETS, 256, 0, stream>>>(counts, tot);
    scan_buckets<<<1, 1024, 0, stream>>>(tot, bbase, N_BUCKETS);
    column_scan<<<N_BUCKETS, 512, 0, stream>>>(counts, bbase, offs);
    block_scatter<<<NCHUNK, 256, 0, stream>>>(src, dst, offs, records, N_EDGES);
    bucket_csr<<<N_BUCKETS, 512, 0, stream>>>(records, bbase, ptr, dinv, csr_src, N_NODES);

    // ---- conversions / weight packing / pool zero ----
    convert_x_pre<<<(N_NODES * (F_IN / 4) + 255) / 256, 256, 0, stream>>>(
        x, dinv, (unsigned int*)x_pre, N_NODES);
    pack_w<<<(F_IN * HDIM + 255) / 256, 256, 0, stream>>>(W1, W1hi, W1lo, F_IN);
    pack_w<<<(HDIM * HDIM + 255) / 256, 256, 0, stream>>>(W2, W2hi, W2lo, HDIM);
    zero_f<<<(N_GRAPHS * HDIM + 255) / 256, 256, 0, stream>>>(pool, N_GRAPHS * HDIM);

    // ---- layer 1: sliced agg (4 slices x 2 node-groups per 8-block set) ----
    csr_agg_sliced<F_IN><<<((N_NODES + 7) / 8) * 8, 256, 0, stream>>>(
        x_pre, ptr, csr_src, dinv, A1, N_NODES);
    gemm_mfma<F_IN, 0><<<(N_NODES + 63) / 64, 256, 0, stream>>>(A1, W1hi, W1lo, b1, dinv,
                                                                h1_pre, N_NODES);
    // ---- layer 2: sliced agg (8 slices) ----
    csr_agg_sliced<HDIM><<<((N_NODES + 3) / 4) * 8, 256, 0, stream>>>(
        h1_pre, ptr, csr_src, dinv, A2, N_NODES);
    gemm_mfma<HDIM, 2><<<(N_NODES + 63) / 64, 256, 0, stream>>>(A2, W2hi, W2lo, b2, dinv,
                                                                h2, N_NODES);

    // ---- pool + head ----
    pool_sum_runs<<<(N_NODES + 127) / 128, 256, 0, stream>>>(h2, batch, pool, N_NODES);
    final_head<<<1, 64, 0, stream>>>(pool, batch, fcw, fcb, out, N_NODES);
}

// Round 13
// 647.068 us; speedup vs baseline: 1.8752x; 1.8752x over previous
//
#include <hip/hip_runtime.h>
#include <cstdint>

#define N_NODES 100000
#define N_EDGES 3200000
#define N_GRAPHS 64
#define HDIM 256
#define F_IN 128

#define BUCKET_BITS 7
#define NPB 128                                 // nodes per bucket
#define N_BUCKETS ((N_NODES + NPB - 1) / NPB)   // 782
#define CHUNK 8192
#define NCHUNK ((N_EDGES + CHUNK - 1) / CHUNK)  // 391

typedef __attribute__((ext_vector_type(8))) short bf16x8;
typedef __attribute__((ext_vector_type(4))) float f32x4;
typedef __attribute__((ext_vector_type(2))) float f32x2;

// ---------------- bf16 helpers ----------------
__device__ __forceinline__ unsigned short f2bf(float f) {
    unsigned int b = __float_as_uint(f);
    b = (b + 0x7FFFu + ((b >> 16) & 1u)) >> 16;
    return (unsigned short)b;
}
__device__ __forceinline__ float bf2f(unsigned short u) {
    return __uint_as_float((unsigned int)u << 16);
}

// ---------------- fp8 e4m3 helpers (HW cvt) ----------------
__device__ __forceinline__ unsigned int pack4_fp8(float a, float b, float c, float d) {
    int v = 0;
    v = __builtin_amdgcn_cvt_pk_fp8_f32(a, b, v, false);  // bytes 0,1
    v = __builtin_amdgcn_cvt_pk_fp8_f32(c, d, v, true);   // bytes 2,3
    return (unsigned int)v;
}
__device__ __forceinline__ unsigned char pack1_fp8(float a) {
    int v = __builtin_amdgcn_cvt_pk_fp8_f32(a, a, 0, false);
    return (unsigned char)(v & 0xFF);
}

// ---------------- utility ----------------
__global__ void zero_f(float* p, int n) {
    int i = blockIdx.x * blockDim.x + threadIdx.x;
    if (i < n) p[i] = 0.0f;
}

// ---------------- atomic-free multisplit CSR build ----------------
__global__ __launch_bounds__(256) void block_count(const int* __restrict__ dst,
                                                   int* __restrict__ counts, int nE) {
    __shared__ int hist[N_BUCKETS];
    int blk = blockIdx.x, t = threadIdx.x;
    for (int i = t; i < N_BUCKETS; i += 256) hist[i] = 0;
    __syncthreads();
    int lo = blk * CHUNK;
    int hi = lo + CHUNK < nE ? lo + CHUNK : nE;
    for (int i = lo + t; i < hi; i += 256) atomicAdd(&hist[dst[i] >> BUCKET_BITS], 1);
    __syncthreads();
    for (int i = t; i < N_BUCKETS; i += 256) counts[blk * N_BUCKETS + i] = hist[i];
}

__global__ __launch_bounds__(256) void bucket_totals(const int* __restrict__ counts,
                                                     int* __restrict__ tot) {
    __shared__ int red[256];
    int b = blockIdx.x, t = threadIdx.x;
    int s = 0;
    for (int blk = t; blk < NCHUNK; blk += 256) s += counts[blk * N_BUCKETS + b];
    red[t] = s;
    __syncthreads();
    for (int o = 128; o > 0; o >>= 1) {
        if (t < o) red[t] += red[t + o];
        __syncthreads();
    }
    if (t == 0) tot[b] = red[0];
}

__global__ __launch_bounds__(1024) void scan_buckets(const int* __restrict__ tot,
                                                     int* __restrict__ base, int nb) {
    __shared__ int lds[1024];
    int t = threadIdx.x;
    int v = (t < nb) ? tot[t] : 0;
    lds[t] = v;
    __syncthreads();
    for (int off = 1; off < 1024; off <<= 1) {
        int a = (t >= off) ? lds[t - off] : 0;
        __syncthreads();
        lds[t] += a;
        __syncthreads();
    }
    int excl = lds[t] - v;
    if (t < nb) base[t] = excl;
    if (t == nb) base[t] = excl;
}

__global__ __launch_bounds__(512) void column_scan(const int* __restrict__ counts,
                                                   const int* __restrict__ base,
                                                   int* __restrict__ offs) {
    __shared__ int lds[512];
    int b = blockIdx.x, t = threadIdx.x;
    int v = (t < NCHUNK) ? counts[t * N_BUCKETS + b] : 0;
    lds[t] = v;
    __syncthreads();
    for (int off = 1; off < 512; off <<= 1) {
        int a = (t >= off) ? lds[t - off] : 0;
        __syncthreads();
        lds[t] += a;
        __syncthreads();
    }
    if (t < NCHUNK) offs[t * N_BUCKETS + b] = base[b] + lds[t] - v;
}

__global__ __launch_bounds__(256) void block_scatter(const int* __restrict__ src,
                                                     const int* __restrict__ dst,
                                                     const int* __restrict__ offs,
                                                     unsigned int* __restrict__ rec, int nE) {
    __shared__ int cur[N_BUCKETS];
    int blk = blockIdx.x, t = threadIdx.x;
    for (int i = t; i < N_BUCKETS; i += 256) cur[i] = offs[blk * N_BUCKETS + i];
    __syncthreads();
    int lo = blk * CHUNK;
    int hi = lo + CHUNK < nE ? lo + CHUNK : nE;
    for (int i = lo + t; i < hi; i += 256) {
        int d = dst[i];
        int b = d >> BUCKET_BITS;
        int pos = atomicAdd(&cur[b], 1);  // LDS atomic
        rec[pos] = (unsigned int)src[i] | ((unsigned int)(d & (NPB - 1)) << 17);
    }
}

__global__ __launch_bounds__(512) void bucket_csr(const unsigned int* __restrict__ rec,
                                                  const int* __restrict__ base,
                                                  int* __restrict__ ptr, float* __restrict__ dinv,
                                                  int* __restrict__ csr_src, int n) {
    __shared__ int hist[NPB];
    __shared__ int sc[NPB];
    __shared__ int cur[NPB];
    int b = blockIdx.x;
    int lo = base[b], hi = base[b + 1];
    int t = threadIdx.x;
    if (t < NPB) hist[t] = 0;
    __syncthreads();
    for (int i = lo + t; i < hi; i += 512) atomicAdd(&hist[rec[i] >> 17], 1);
    __syncthreads();
    if (t < NPB) sc[t] = hist[t];
    __syncthreads();
    for (int off = 1; off < NPB; off <<= 1) {
        int a = (t < NPB && t >= off) ? sc[t - off] : 0;
        __syncthreads();
        if (t < NPB) sc[t] += a;
        __syncthreads();
    }
    if (t < NPB) {
        int node = b * NPB + t;
        int incl = sc[t];
        int excl = incl - hist[t];
        if (node < n) {
            ptr[node] = lo + incl;
            dinv[node] = rsqrtf((float)hist[t] + 1.0f);
        }
        cur[t] = lo + excl;
    }
    __syncthreads();
    for (int i = lo + t; i < hi; i += 512) {
        unsigned int r = rec[i];
        int pos = atomicAdd(&cur[r >> 17], 1);
        csr_src[pos] = (int)(r & 0x1FFFFu);
    }
}

// ---------------- x -> fp8 pre-scaled: x_pre[n] = fp8(dinv[n] * x[n]) ----------------
__global__ void convert_x_pre(const float* __restrict__ x, const float* __restrict__ dinv,
                              unsigned int* __restrict__ xp, int n) {
    int tid = blockIdx.x * blockDim.x + threadIdx.x;  // over n*F_IN/4
    if (tid >= n * (F_IN / 4)) return;
    int node = tid / (F_IN / 4);
    float di = dinv[node];
    float4 v = ((const float4*)x)[tid];
    xp[tid] = pack4_fp8(v.x * di, v.y * di, v.z * di, v.w * di);
}

// ---------------- pack W[K][256] fp32 -> hi/lo bf16 in MFMA B-fragment order ----------------
__global__ void pack_w(const float* __restrict__ W, unsigned short* __restrict__ hi,
                       unsigned short* __restrict__ lo, int K) {
    int idx = blockIdx.x * blockDim.x + threadIdx.x;
    if (idx >= K * HDIM) return;
    int k = idx >> 8, c = idx & 255;
    float w = W[idx];
    unsigned short h = f2bf(w);
    float hf = __uint_as_float((unsigned int)h << 16);
    unsigned short l = f2bf(w - hf);
    int pos = ((k >> 5) * 16 + (c >> 4)) * 512 + ((((k >> 3) & 3) * 16) + (c & 15)) * 8 + (k & 7);
    hi[pos] = h;
    lo[pos] = l;
}

// ---------------- aggregation (fp8 in, bf16 out), 16-deep load pipeline ----------------
__global__ void csr_agg128_fp8(const unsigned char* __restrict__ h, const int* __restrict__ ptr,
                               const int* __restrict__ csr, const float* __restrict__ dinv,
                               unsigned short* __restrict__ out, int n) {
    int wave = threadIdx.x >> 6, lane = threadIdx.x & 63;
    int node = blockIdx.x * 4 + wave;
    if (node >= n) return;
    int begin = node ? ptr[node - 1] : 0;
    int end = ptr[node];
    unsigned int u = *(const unsigned short*)(h + (size_t)node * 128 + lane * 2);
    f32x2 a01 = __builtin_amdgcn_cvt_pk_f32_fp8((int)u, false);
    int i = begin;
    for (; i + 16 <= end; i += 16) {
        unsigned int uu[16];
#pragma unroll
        for (int j = 0; j < 16; j++) {
            int s = csr[i + j];
            uu[j] = *(const unsigned short*)(h + (size_t)s * 128 + lane * 2);
        }
#pragma unroll
        for (int j = 0; j < 16; j++)
            a01 += __builtin_amdgcn_cvt_pk_f32_fp8((int)uu[j], false);
    }
    for (; i + 4 <= end; i += 4) {
        unsigned int uu[4];
#pragma unroll
        for (int j = 0; j < 4; j++) {
            int s = csr[i + j];
            uu[j] = *(const unsigned short*)(h + (size_t)s * 128 + lane * 2);
        }
#pragma unroll
        for (int j = 0; j < 4; j++)
            a01 += __builtin_amdgcn_cvt_pk_f32_fp8((int)uu[j], false);
    }
    for (; i < end; i++) {
        int s = csr[i];
        unsigned int u0 = *(const unsigned short*)(h + (size_t)s * 128 + lane * 2);
        a01 += __builtin_amdgcn_cvt_pk_f32_fp8((int)u0, false);
    }
    float dn = dinv[node];
    unsigned int o = (unsigned int)f2bf(a01.x * dn) | ((unsigned int)f2bf(a01.y * dn) << 16);
    *(unsigned int*)(out + (size_t)node * 128 + lane * 2) = o;
}

__global__ void csr_agg256_fp8(const unsigned char* __restrict__ h, const int* __restrict__ ptr,
                               const int* __restrict__ csr, const float* __restrict__ dinv,
                               unsigned short* __restrict__ out, int n) {
    int wave = threadIdx.x >> 6, lane = threadIdx.x & 63;
    int node = blockIdx.x * 4 + wave;
    if (node >= n) return;
    int begin = node ? ptr[node - 1] : 0;
    int end = ptr[node];
    unsigned int u = *(const unsigned int*)(h + (size_t)node * 256 + lane * 4);
    f32x2 a01 = __builtin_amdgcn_cvt_pk_f32_fp8((int)u, false);
    f32x2 a23 = __builtin_amdgcn_cvt_pk_f32_fp8((int)u, true);
    int i = begin;
    for (; i + 16 <= end; i += 16) {
        unsigned int uu[16];
#pragma unroll
        for (int j = 0; j < 16; j++) {
            int s = csr[i + j];
            uu[j] = *(const unsigned int*)(h + (size_t)s * 256 + lane * 4);
        }
#pragma unroll
        for (int j = 0; j < 16; j++) {
            a01 += __builtin_amdgcn_cvt_pk_f32_fp8((int)uu[j], false);
            a23 += __builtin_amdgcn_cvt_pk_f32_fp8((int)uu[j], true);
        }
    }
    for (; i + 4 <= end; i += 4) {
        unsigned int uu[4];
#pragma unroll
        for (int j = 0; j < 4; j++) {
            int s = csr[i + j];
            uu[j] = *(const unsigned int*)(h + (size_t)s * 256 + lane * 4);
        }
#pragma unroll
        for (int j = 0; j < 4; j++) {
            a01 += __builtin_amdgcn_cvt_pk_f32_fp8((int)uu[j], false);
            a23 += __builtin_amdgcn_cvt_pk_f32_fp8((int)uu[j], true);
        }
    }
    for (; i < end; i++) {
        int s = csr[i];
        unsigned int u0 = *(const unsigned int*)(h + (size_t)s * 256 + lane * 4);
        a01 += __builtin_amdgcn_cvt_pk_f32_fp8((int)u0, false);
        a23 += __builtin_amdgcn_cvt_pk_f32_fp8((int)u0, true);
    }
    float dn = dinv[node];
    uint2 o;
    o.x = (unsigned int)f2bf(a01.x * dn) | ((unsigned int)f2bf(a01.y * dn) << 16);
    o.y = (unsigned int)f2bf(a23.x * dn) | ((unsigned int)f2bf(a23.y * dn) << 16);
    *(uint2*)(out + (size_t)node * 256 + lane * 4) = o;
}

// ---------------- MFMA GEMM: act(A[n,K] @ (Whi+Wlo) + b) ----------------
// block: 4 waves = 64 rows x 256 cols; wave: 32 rows (2 strips) x 128 cols (8 ct)
// MODE 0: out fp8 = fp8(dinv[row]*relu(v))   (layer-1, feeds agg256)
// MODE 2: out bf16 = bf16(relu(v))           (layer-2, feeds pooling)
template <int K, int MODE>
__global__ __launch_bounds__(256, 3) void gemm_mfma(
    const unsigned short* __restrict__ A, const unsigned short* __restrict__ Whi,
    const unsigned short* __restrict__ Wlo, const float* __restrict__ bias,
    const float* __restrict__ dinv, void* __restrict__ outp, int n) {
    int wave = threadIdx.x >> 6, lane = threadIdx.x & 63;
    int quad = lane >> 4, l16 = lane & 15;
    int rowgrp = wave >> 1, colhalf = wave & 1;
    int rowbase = blockIdx.x * 64 + rowgrp * 32;

    f32x4 acc[2][8];
#pragma unroll
    for (int s = 0; s < 2; s++)
#pragma unroll
        for (int ct = 0; ct < 8; ct++) acc[s][ct] = (f32x4){0.f, 0.f, 0.f, 0.f};

    int r0 = rowbase + l16;
    int r1 = rowbase + 16 + l16;
    int rc0 = r0 < n ? r0 : n - 1;
    int rc1 = r1 < n ? r1 : n - 1;

    for (int kt = 0; kt < K / 32; kt++) {
        bf16x8 a0 = *(const bf16x8*)(A + (size_t)rc0 * K + kt * 32 + quad * 8);
        bf16x8 a1 = *(const bf16x8*)(A + (size_t)rc1 * K + kt * 32 + quad * 8);
        const unsigned short* wh = Whi + ((size_t)kt * 16 + colhalf * 8) * 512 + lane * 8;
        const unsigned short* wl = Wlo + ((size_t)kt * 16 + colhalf * 8) * 512 + lane * 8;
#pragma unroll
        for (int ct = 0; ct < 8; ct++) {
            bf16x8 bh = *(const bf16x8*)(wh + ct * 512);
            bf16x8 bl = *(const bf16x8*)(wl + ct * 512);
            acc[0][ct] = __builtin_amdgcn_mfma_f32_16x16x32_bf16(a0, bh, acc[0][ct], 0, 0, 0);
            acc[0][ct] = __builtin_amdgcn_mfma_f32_16x16x32_bf16(a0, bl, acc[0][ct], 0, 0, 0);
            acc[1][ct] = __builtin_amdgcn_mfma_f32_16x16x32_bf16(a1, bh, acc[1][ct], 0, 0, 0);
            acc[1][ct] = __builtin_amdgcn_mfma_f32_16x16x32_bf16(a1, bl, acc[1][ct], 0, 0, 0);
        }
    }

#pragma unroll
    for (int s = 0; s < 2; s++) {
#pragma unroll
        for (int ct = 0; ct < 8; ct++) {
            int col = colhalf * 128 + ct * 16 + l16;
            float b = bias[col];
#pragma unroll
            for (int r = 0; r < 4; r++) {
                int row = rowbase + s * 16 + quad * 4 + r;
                if (row < n) {
                    float v = acc[s][ct][r] + b;
                    v = v > 0.0f ? v : 0.0f;
                    if (MODE == 0) {
                        ((unsigned char*)outp)[(size_t)row * HDIM + col] = pack1_fp8(v * dinv[row]);
                    } else {
                        ((unsigned short*)outp)[(size_t)row * HDIM + col] = f2bf(v);
                    }
                }
            }
        }
    }
}

// ---------------- pooling (batch sorted -> run-length), bf16 input ----------------
__global__ void pool_sum_runs(const unsigned short* __restrict__ h, const int* __restrict__ batch,
                              float* __restrict__ pool, int n) {
    constexpr int ROWS = 128;
    int f = threadIdx.x;
    int r0 = blockIdx.x * ROWS;
    int rend = r0 + ROWS;
    if (rend > n) rend = n;
    float acc = 0.0f;
    int cur = batch[r0];
    for (int r = r0; r < rend; r++) {
        int g = batch[r];
        if (g != cur) {
            atomicAdd(&pool[cur * HDIM + f], acc);
            acc = 0.0f; cur = g;
        }
        acc += bf2f(h[(size_t)r * HDIM + f]);
    }
    atomicAdd(&pool[cur * HDIM + f], acc);
}

// ---------------- head: mean (cnt via binary search on sorted batch) + FC + log_softmax ----
__global__ void final_head(const float* __restrict__ pool, const int* __restrict__ batch,
                           const float* __restrict__ fcw, const float* __restrict__ fcb,
                           float* __restrict__ out, int n) {
    int g = threadIdx.x;
    if (g < N_GRAPHS) {
        int lo = 0, hi = n;
        while (lo < hi) { int m = (lo + hi) >> 1; if (batch[m] < g) lo = m + 1; else hi = m; }
        int b0 = lo;
        lo = 0; hi = n;
        while (lo < hi) { int m = (lo + hi) >> 1; if (batch[m] < g + 1) lo = m + 1; else hi = m; }
        int c = lo - b0;
        float cf = c > 1 ? (float)c : 1.0f;
        float inv = 1.0f / cf;
        float l0 = fcb[0], l1 = fcb[1];
        for (int f = 0; f < HDIM; f++) {
            float p = pool[g * HDIM + f] * inv;
            l0 += p * fcw[f * 2 + 0];
            l1 += p * fcw[f * 2 + 1];
        }
        float m = fmaxf(l0, l1);
        float lse = m + logf(expf(l0 - m) + expf(l1 - m));
        out[g * 2 + 0] = l0 - lse;
        out[g * 2 + 1] = l1 - lse;
    }
}

extern "C" void kernel_launch(void* const* d_in, const int* in_sizes, int n_in,
                              void* d_out, int out_size, void* d_ws, size_t ws_size,
                              hipStream_t stream) {
    const float* x = (const float*)d_in[0];
    const int* ei = (const int*)d_in[1];
    const int* batch = (const int*)d_in[2];
    const float* W1 = (const float*)d_in[3];
    const float* b1 = (const float*)d_in[4];
    const float* W2 = (const float*)d_in[5];
    const float* b2 = (const float*)d_in[6];
    const float* fcw = (const float*)d_in[7];
    const float* fcb = (const float*)d_in[8];
    float* out = (float*)d_out;

    const int* src = ei;
    const int* dst = ei + N_EDGES;

    // ---- workspace layout (bytes) ----
    char* ws = (char*)d_ws;
    float* dinv = (float*)ws;            ws += 4 * ((N_NODES + 255) & ~255);
    int* ptr = (int*)ws;                 ws += 4 * ((N_NODES + 255) & ~255);
    int* csr_src = (int*)ws;             ws += 4 * (size_t)N_EDGES;
    int* counts = (int*)ws;              ws += 4 * (size_t)NCHUNK * N_BUCKETS;
    int* offs = (int*)ws;                ws += 4 * (size_t)NCHUNK * N_BUCKETS;
    int* tot = (int*)ws;                 ws += 4 * 1024;
    int* bbase = (int*)ws;               ws += 4 * 1024;
    unsigned short* W1hi = (unsigned short*)ws; ws += 2 * F_IN * HDIM;
    unsigned short* W1lo = (unsigned short*)ws; ws += 2 * F_IN * HDIM;
    unsigned short* W2hi = (unsigned short*)ws; ws += 2 * HDIM * HDIM;
    unsigned short* W2lo = (unsigned short*)ws; ws += 2 * HDIM * HDIM;
    float* pool = (float*)ws;            ws += 4 * N_GRAPHS * HDIM;
    // R0 region (102.4MB): x_pre fp8 | A1 bf16 | h1_pre fp8; later h2 bf16 overlays start
    char* R0 = ws;                       ws += 4 * (size_t)N_NODES * HDIM;
    unsigned char* x_pre = (unsigned char*)R0;                                 // N*128 fp8
    unsigned short* A1 = (unsigned short*)(R0 + (size_t)N_NODES * F_IN);       // N*128 bf16
    unsigned char* h1_pre = (unsigned char*)(R0 + 3 * (size_t)N_NODES * F_IN); // N*256 fp8
    unsigned short* h2 = (unsigned short*)R0;                                  // N*256 bf16
    unsigned short* A2 = (unsigned short*)ws;  // N*256 bf16 (layer 2 only)
    // records overlay A2 (dead until layer 2): N_EDGES*4 = 12.8MB <= 51.2MB
    unsigned int* records = (unsigned int*)A2;

    // ---- atomic-free bucketed CSR build + dinv ----
    block_count<<<NCHUNK, 256, 0, stream>>>(dst, counts, N_EDGES);
    bucket_totals<<<N_BUCKETS, 256, 0, stream>>>(counts, tot);
    scan_buckets<<<1, 1024, 0, stream>>>(tot, bbase, N_BUCKETS);
    column_scan<<<N_BUCKETS, 512, 0, stream>>>(counts, bbase, offs);
    block_scatter<<<NCHUNK, 256, 0, stream>>>(src, dst, offs, records, N_EDGES);
    bucket_csr<<<N_BUCKETS, 512, 0, stream>>>(records, bbase, ptr, dinv, csr_src, N_NODES);

    // ---- conversions / weight packing / pool zero ----
    convert_x_pre<<<(N_NODES * (F_IN / 4) + 255) / 256, 256, 0, stream>>>(
        x, dinv, (unsigned int*)x_pre, N_NODES);
    pack_w<<<(F_IN * HDIM + 255) / 256, 256, 0, stream>>>(W1, W1hi, W1lo, F_IN);
    pack_w<<<(HDIM * HDIM + 255) / 256, 256, 0, stream>>>(W2, W2hi, W2lo, HDIM);
    zero_f<<<(N_GRAPHS * HDIM + 255) / 256, 256, 0, stream>>>(pool, N_GRAPHS * HDIM);

    // ---- layer 1 ----
    csr_agg128_fp8<<<(N_NODES + 3) / 4, 256, 0, stream>>>(x_pre, ptr, csr_src, dinv, A1, N_NODES);
    gemm_mfma<F_IN, 0><<<(N_NODES + 63) / 64, 256, 0, stream>>>(A1, W1hi, W1lo, b1, dinv,
                                                                h1_pre, N_NODES);
    // ---- layer 2 ----
    csr_agg256_fp8<<<(N_NODES + 3) / 4, 256, 0, stream>>>(h1_pre, ptr, csr_src, dinv, A2, N_NODES);
    gemm_mfma<HDIM, 2><<<(N_NODES + 63) / 64, 256, 0, stream>>>(A2, W2hi, W2lo, b2, dinv,
                                                                h2, N_NODES);

    // ---- pool + head ----
    pool_sum_runs<<<(N_NODES + 127) / 128, 256, 0, stream>>>(h2, batch, pool, N_NODES);
    final_head<<<1, 64, 0, stream>>>(pool, batch, fcw, fcb, out, N_NODES);
}